// Round 10
// baseline (699.840 us; speedup 1.0000x reference)
//
#include <hip/hip_runtime.h>

#define B_ 16
#define N_ 16384
#define K_ 16

// ---- compact workspace layout (float offsets) ----
enum : int {
  WS_LAT  = 0,      // 32 x 128 latent (f32, atomicMax-as-uint, relu>=0)
  WS_SEL  = 5632,   // 32 x 48 selected keypoints
  WS_PMIN = 7168,   // 16 x 3
  WS_PMAX = 7216,   // 16 x 3
  WS_CF   = 7264,   // 16 x 512 x 3 cage corners
  WS_W1F  = 31840,  // 64 x 3  bn-folded
  WS_B1F  = 32032,  // 64
  WS_W2T  = 32096,  // 64(c_in) x 128(out) TRANSPOSED, bn-folded
  WS_B2F  = 40288,  // 128
  WS_W3F  = 40416,  // 128(c_in) x 128(out), transposed, scale3-folded
  WS_B3F  = 56800,  // 128
  WS_END  = 56928
};

enum : int { OUT_DEF=0, OUT_SRCKP=786432, OUT_TGTKP=787200 };

__device__ __forceinline__ float dist2rn(float px,float py,float pz,float sx,float sy,float sz){
  float dx=__fsub_rn(px,sx), dy=__fsub_rn(py,sy), dz=__fsub_rn(pz,sz);
  return __fadd_rn(__fadd_rn(__fmul_rn(dx,dx),__fmul_rn(dy,dy)),__fmul_rn(dz,dz));
}

// ---------------- prep: fold BN into encoder weights, transpose w2/w3 ---------
struct EncW {
  const float *w1,*b1,*g1,*be1,*m1,*v1;
  const float *w2,*b2,*g2,*be2,*m2,*v2;
  const float *w3,*b3,*g3,*be3,*m3,*v3;
};

__device__ __forceinline__ float bn_scale(const float* g, const float* v, int ch){
  return g[ch] * (1.0f / sqrtf(v[ch] + 1e-5f));
}

__global__ void prep_kernel(EncW a, float* ws){
  const int stride = gridDim.x*blockDim.x;
  const int tid = blockIdx.x*blockDim.x + threadIdx.x;
  for (int i=tid;i<4096;i+=stride)            // zero latent (atomicMax target)
    ws[WS_LAT+i] = 0.0f;
  for (int i=tid;i<192;i+=stride){            // W1F
    int o=i/3;
    ws[WS_W1F+i] = a.w1[i] * bn_scale(a.g1,a.v1,o);
  }
  for (int i=tid;i<64;i+=stride){             // B1F = (b1-m1)*s1+be1
    float s = bn_scale(a.g1,a.v1,i);
    ws[WS_B1F+i] = (a.b1[i] - a.m1[i])*s + a.be1[i];
  }
  for (int i=tid;i<8192;i+=stride){           // W2T[c][o] = w2[o][c]*s2[o]
    int c=i>>7, o=i&127;
    ws[WS_W2T+i] = a.w2[o*64+c] * bn_scale(a.g2,a.v2,o);
  }
  for (int i=tid;i<128;i+=stride){
    float s = bn_scale(a.g2,a.v2,i);
    ws[WS_B2F+i] = (a.b2[i] - a.m2[i])*s + a.be2[i];
  }
  for (int i=tid;i<16384;i+=stride){          // W3F[c][j] = w3[j][c]*s3[j]
    int c=i>>7, j=i&127;
    ws[WS_W3F+i] = a.w3[j*128+c] * bn_scale(a.g3,a.v3,j);
  }
  for (int i=tid;i<128;i+=stride){
    float s = bn_scale(a.g3,a.v3,i);
    ws[WS_B3F+i] = (a.b3[i] - a.m3[i])*s + a.be3[i];
  }
}

// ---------------- encoder v6: 64-pt tile, full-h2 LDS, h1 in halves -----------
// R9 post-mortem: P=1 quarter-churn doubled ds_reads/point (384) + tile
// overhead; occupancy rose but VALU issue rose too. v6: 64-pt tile, P=1, but
// h2 FULLY resident (32KB) and h1 streamed in two 8KB halves -> LDS 40KB
// (4 blocks/CU), only 5 barriers/tile, 192 ds_read : 6144 fmac per lane.
// acc2[32] dies before accL[32] lives -> ~55 VGPR, no AGPR pressure.
// Accumulation chains (c, c2 ascending) bit-identical to v3/v4/v5.
__global__ __launch_bounds__(256, 4) void encode_kernel(const float* __restrict__ src,
                                                        const float* __restrict__ tgt,
                                                        const float* __restrict__ ws,
                                                        float* __restrict__ lat){
  const int cloud = blockIdx.y;
  const int tile  = blockIdx.x;              // 256 tiles/cloud, 64 pts each
  const int t = threadIdx.x;
  const int lane = t & 63;
  const int wv = __builtin_amdgcn_readfirstlane(t >> 6);   // 0..3

  const float* base = ((cloud < B_) ? (src + (size_t)cloud*N_*3)
                                    : (tgt + (size_t)(cloud-B_)*N_*3))
                      + (size_t)tile*64*3;

  __shared__ float h1h[32*64];    // [half-ch][pt]  8KB (two sequential halves)
  __shared__ float h2f[128*64];   // [ch][pt] 32KB  (full h2)

  const float x0=base[lane*3+0], x1=base[lane*3+1], x2=base[lane*3+2];

  float acc2[32];
  #pragma unroll
  for (int oo=0;oo<32;oo++) acc2[oo]=0.0f;

  #pragma unroll 1
  for (int h=0; h<2; h++){
    // phase A (half h): layer-1 channels h*32 + wv*8 + k
    {
      const float* w1 = ws + WS_W1F;
      #pragma unroll
      for (int k=0;k<8;k++){
        const int o = h*32 + wv*8 + k;
        float a = fmaf(w1[o*3+2],x2, fmaf(w1[o*3+1],x1, w1[o*3]*x0)) + ws[WS_B1F+o];
        h1h[(wv*8+k)*64 + lane] = fmaxf(a, 0.0f);
      }
    }
    __syncthreads();
    // phase B (half h): accumulate h2 channels wv*32..+31 over c in this half
    {
      const float* w2t = ws + WS_W2T + wv*32;
      #pragma unroll 2
      for (int c=0;c<32;c++){
        const float v = h1h[c*64 + lane];
        const float* wrow = w2t + (h*32+c)*128;
        #pragma unroll
        for (int oo=0;oo<32;oo++)
          acc2[oo] = fmaf(wrow[oo], v, acc2[oo]);
      }
    }
    __syncthreads();   // h1h fully consumed before next half overwrites
  }

  // h2 bias+relu -> LDS
  #pragma unroll
  for (int oo=0;oo<32;oo++)
    h2f[(wv*32+oo)*64 + lane] = fmaxf(acc2[oo] + ws[WS_B2F + wv*32 + oo], 0.0f);
  __syncthreads();

  // phase C: layer 3 over all 128 input channels (wave owns latent wv*32..+31)
  float accL[32];
  #pragma unroll
  for (int jj=0;jj<32;jj++) accL[jj]=0.0f;
  {
    const float* w3 = ws + WS_W3F + wv*32;
    #pragma unroll 2
    for (int c2=0;c2<128;c2++){
      const float v = h2f[c2*64 + lane];
      const float* wrow = w3 + c2*128;
      #pragma unroll
      for (int jj=0;jj<32;jj++)
        accL[jj] = fmaf(wrow[jj], v, accL[jj]);
    }
  }

  // bias+relu, wave-reduce 64 lanes (=64 points), one atomic per channel
  #pragma unroll
  for (int jj=0;jj<32;jj++){
    float x = fmaxf(accL[jj] + ws[WS_B3F + wv*32 + jj], 0.0f);  // >=0: uint order ok
    #pragma unroll
    for (int off=32; off>0; off>>=1) x = fmaxf(x, __shfl_down(x, off, 64));
    if (lane==0)
      atomicMax((unsigned*)(lat + cloud*128 + wv*32 + jj), __float_as_uint(x));
  }
}

// ---------------- FPS + fused kp-MLP + fused src min/max ----------------------
// One block (512 thr) per cloud; points register-cached once (no global
// re-read across the 16 rounds). Argmax: LDS dump + single-wave butterfly.
// Tie-break: larger v, then smaller index == numpy argmax first-occurrence.
__global__ __launch_bounds__(512) void fps_kernel(const float* __restrict__ src,
                                                  const float* __restrict__ tgt,
                                                  const float* __restrict__ kw1,
                                                  const float* __restrict__ kb1,
                                                  const float* __restrict__ kw2,
                                                  const float* __restrict__ kb2,
                                                  float* ws, float* out){
  const int cloud = blockIdx.x; const int t = threadIdx.x;
  const float* base = (cloud < B_) ? (src + (size_t)cloud*N_*3)
                                   : (tgt + (size_t)(cloud-B_)*N_*3);
  __shared__ float kpl[48];
  __shared__ float h[128];
  __shared__ float rv[512]; __shared__ int ri[512];
  __shared__ float sel[3];

  // register-cache this thread's 32 points (issue loads early)
  float px[32], py[32], pz[32];
  #pragma unroll
  for (int k=0;k<32;k++){
    int n = t + k*512;
    px[k]=base[n*3]; py[k]=base[n*3+1]; pz[k]=base[n*3+2];
  }

  // fused kp MLP: lat(128) -> 128 relu -> 48  (same fmaf chains as before)
  const float* lat = ws + WS_LAT + cloud*128;
  if (t < 128){
    float acc = kb1[t];
    const float* w = kw1 + t*128;
    for (int c=0;c<128;c++) acc = fmaf(lat[c], w[c], acc);
    h[t] = fmaxf(acc, 0.0f);
  }
  __syncthreads();
  if (t < 48){
    float acc = kb2[t];
    const float* w = kw2 + t*128;
    for (int c=0;c<128;c++) acc = fmaf(h[c], w[c], acc);
    kpl[t] = acc;
  }
  __syncthreads();

  // phase A: d0 = min over proposed kps, argmax; src clouds also min/max
  float mnx=3.4e38f,mny=3.4e38f,mnz=3.4e38f, mxx=-3.4e38f,mxy=-3.4e38f,mxz=-3.4e38f;
  float bv = -1.0f; int bi = 0;
  #pragma unroll 2
  for (int k=0;k<32;k++){
    int n = t + k*512;
    if (cloud < B_){
      mnx=fminf(mnx,px[k]); mny=fminf(mny,py[k]); mnz=fminf(mnz,pz[k]);
      mxx=fmaxf(mxx,px[k]); mxy=fmaxf(mxy,py[k]); mxz=fmaxf(mxz,pz[k]);
    }
    float dmin = 3.4028235e38f;
    #pragma unroll
    for (int j=0;j<K_;j++)
      dmin = fminf(dmin, dist2rn(px[k],py[k],pz[k], kpl[j*3],kpl[j*3+1],kpl[j*3+2]));
    if (dmin > bv){ bv = dmin; bi = n; }
  }

  // block argmax -> sel, also store keypoint 0
  rv[t]=bv; ri[t]=bi;
  __syncthreads();
  if (t < 64){
    float v = rv[t]; int i = ri[t];
    #pragma unroll
    for (int e=1;e<8;e++){
      float v2=rv[t+64*e]; int i2=ri[t+64*e];
      if (v2 > v || (v2 == v && i2 < i)){ v=v2; i=i2; }
    }
    #pragma unroll
    for (int m=1;m<64;m<<=1){
      float v2=__shfl_xor(v,m,64); int i2=__shfl_xor(i,m,64);
      if (v2 > v || (v2 == v && i2 < i)){ v=v2; i=i2; }
    }
    if (t==0){
      sel[0]=base[i*3]; sel[1]=base[i*3+1]; sel[2]=base[i*3+2];
      float* sw = ws + WS_SEL + cloud*48;
      sw[0]=sel[0]; sw[1]=sel[1]; sw[2]=sel[2];
      size_t o = (cloud<B_) ? (size_t)(OUT_SRCKP + cloud*48) : (size_t)(OUT_TGTKP + (cloud-B_)*48);
      out[o]=sel[0]; out[o+1]=sel[1]; out[o+2]=sel[2];
    }
  }
  __syncthreads();

  // src-cloud min/max block reductions (exact regardless of order)
  if (cloud < B_){
    float vals[6] = {mnx,mny,mnz,mxx,mxy,mxz};
    for (int c=0;c<6;c++){
      rv[t]=vals[c];
      __syncthreads();
      if (t < 64){
        float v = rv[t];
        #pragma unroll
        for (int e=1;e<8;e++){
          float v2 = rv[t+64*e];
          v = (c<3) ? fminf(v,v2) : fmaxf(v,v2);
        }
        #pragma unroll
        for (int m=1;m<64;m<<=1){
          float v2=__shfl_xor(v,m,64);
          v = (c<3) ? fminf(v,v2) : fmaxf(v,v2);
        }
        if (t==0){
          if (c<3) ws[WS_PMIN + cloud*3 + c] = v;
          else     ws[WS_PMAX + cloud*3 + (c-3)] = v;
        }
      }
      __syncthreads();
    }
  }

  float s0=sel[0], s1=sel[1], s2=sel[2];

  // phase B: mind = dist to sel0 (fresh, per reference), track argmax
  float mind[32];
  bv = -1.0f; bi = 0;
  #pragma unroll
  for (int k=0;k<32;k++){
    int n = t + k*512;
    float d = dist2rn(px[k],py[k],pz[k], s0,s1,s2);
    mind[k]=d;
    if (d > bv){ bv=d; bi=n; }
  }

  for (int it=1; it<K_; it++){
    rv[t]=bv; ri[t]=bi;
    __syncthreads();
    if (t < 64){
      float v = rv[t]; int i = ri[t];
      #pragma unroll
      for (int e=1;e<8;e++){
        float v2=rv[t+64*e]; int i2=ri[t+64*e];
        if (v2 > v || (v2 == v && i2 < i)){ v=v2; i=i2; }
      }
      #pragma unroll
      for (int m=1;m<64;m<<=1){
        float v2=__shfl_xor(v,m,64); int i2=__shfl_xor(i,m,64);
        if (v2 > v || (v2 == v && i2 < i)){ v=v2; i=i2; }
      }
      if (t==0){
        sel[0]=base[i*3]; sel[1]=base[i*3+1]; sel[2]=base[i*3+2];
        float* sw = ws + WS_SEL + cloud*48 + it*3;
        sw[0]=sel[0]; sw[1]=sel[1]; sw[2]=sel[2];
        size_t o = (cloud<B_) ? (size_t)(OUT_SRCKP + cloud*48 + it*3)
                              : (size_t)(OUT_TGTKP + (cloud-B_)*48 + it*3);
        out[o]=sel[0]; out[o+1]=sel[1]; out[o+2]=sel[2];
      }
    }
    __syncthreads();
    s0=sel[0]; s1=sel[1]; s2=sel[2];
    if (it < K_-1){
      bv=-1.0f; bi=0;
      #pragma unroll
      for (int k=0;k<32;k++){
        int n = t + k*512;
        float d = dist2rn(px[k],py[k],pz[k], s0,s1,s2);
        float m = fminf(mind[k], d);
        mind[k]=m;
        if (m > bv){ bv=m; bi=n; }
      }
    }
  }
}

// ---------------- cage MLP + corner grid (64 blocks) --------------------------
__global__ void cage_mlp_kernel(const float* __restrict__ ws,
                                const float* __restrict__ cw1, const float* __restrict__ cb1,
                                const float* __restrict__ cw2, const float* __restrict__ cb2,
                                float* __restrict__ wsm){
  const int b = blockIdx.x >> 2, part = blockIdx.x & 3;
  const int t = threadIdx.x;
  __shared__ float diff[48]; __shared__ float h[128];
  if (t<48) diff[t] = __fsub_rn(ws[WS_SEL + (B_+b)*48 + t], ws[WS_SEL + b*48 + t]);
  __syncthreads();
  if (t<128){
    const float* w = cw1 + t*48;
    float acc = cb1[t];
    for (int j=0;j<48;j++) acc = fmaf(diff[j], w[j], acc);
    h[t] = fmaxf(acc, 0.0f);
  }
  __syncthreads();
  for (int o = part*384 + t; o < part*384 + 384; o += 256){
    const float* w = cw2 + o*128;
    float acc = cb2[o];
    for (int c=0;c<128;c++) acc = fmaf(h[c], w[c], acc);
    int flat = o/3, coord = o - flat*3;
    int u = flat>>6, v=(flat>>3)&7, z=flat&7;
    int g = (coord==0)?u:((coord==1)?v:z);
    float gv = (g==7)?1.0f:(float)g*(1.0f/7.0f);
    wsm[WS_CF + b*1536 + o] = gv + acc;
  }
}

// ---------------- trilinear cage deform ---------------------------------------
__global__ __launch_bounds__(256) void deform_kernel(const float* __restrict__ src,
                                                     const float* __restrict__ ws,
                                                     float* __restrict__ out){
  const int b = blockIdx.y;
  const int n = blockIdx.x*256 + threadIdx.x;
  __shared__ float cf[1536];
  for (int i=threadIdx.x;i<1536;i+=256) cf[i] = ws[WS_CF + b*1536 + i];
  __syncthreads();

  const float* p = src + ((size_t)b*N_ + n)*3;
  float pt[3]; int id[3]; float w[3];
  #pragma unroll
  for (int c=0;c<3;c++){
    float pv = p[c];
    float mn = ws[WS_PMIN+b*3+c], mxv = ws[WS_PMAX+b*3+c];
    float denom = __fadd_rn(__fsub_rn(mxv, mn), 1e-6f);
    float tc = __fmul_rn(__fdiv_rn(__fsub_rn(pv, mn), denom), 7.0f);
    int ic = (int)tc; ic = min(max(ic,0),6);
    pt[c]=pv; id[c]=ic; w[c]=__fsub_rn(tc, (float)ic);
  }
  const int flat = (id[0]<<6) + (id[1]<<3) + id[2];
  const float* c000 = cf + flat*3;
  const float wx=w[0], wy=w[1], wz=w[2];
  const float ux=__fsub_rn(1.0f,wx), uy=__fsub_rn(1.0f,wy), uz=__fsub_rn(1.0f,wz);
  const float w000=__fmul_rn(__fmul_rn(ux,uy),uz);
  const float w100=__fmul_rn(__fmul_rn(wx,uy),uz);
  const float w010=__fmul_rn(__fmul_rn(ux,wy),uz);
  const float w110=__fmul_rn(__fmul_rn(wx,wy),uz);
  const float w001=__fmul_rn(__fmul_rn(ux,uy),wz);
  const float w101=__fmul_rn(__fmul_rn(wx,uy),wz);
  const float w011=__fmul_rn(__fmul_rn(ux,wy),wz);
  const float w111=__fmul_rn(__fmul_rn(wx,wy),wz);
  #pragma unroll
  for (int c=0;c<3;c++){
    float d = __fmul_rn(w000, c000[c]);
    d = __fadd_rn(d, __fmul_rn(w100, c000[192+c]));  // (+1,0,0) -> +64*3
    d = __fadd_rn(d, __fmul_rn(w010, c000[24+c]));   // (0,+1,0) -> +8*3
    d = __fadd_rn(d, __fmul_rn(w110, c000[216+c]));
    d = __fadd_rn(d, __fmul_rn(w001, c000[3+c]));    // (0,0,+1) -> +3
    d = __fadd_rn(d, __fmul_rn(w101, c000[195+c]));
    d = __fadd_rn(d, __fmul_rn(w011, c000[27+c]));
    d = __fadd_rn(d, __fmul_rn(w111, c000[219+c]));
    out[((size_t)b*N_+n)*3 + c] = __fadd_rn(pt[c], d);
  }
}

// ---------------- launch ------------------------------------------------------
extern "C" void kernel_launch(void* const* d_in, const int* in_sizes, int n_in,
                              void* d_out, int out_size, void* d_ws, size_t ws_size,
                              hipStream_t stream){
  const float* src = (const float*)d_in[0];
  const float* tgt = (const float*)d_in[1];
  float* ws = (float*)d_ws;
  float* out = (float*)d_out;

  EncW ew;
  ew.w1 =(const float*)d_in[2];  ew.b1 =(const float*)d_in[3];
  ew.g1 =(const float*)d_in[4];  ew.be1=(const float*)d_in[5];
  ew.m1 =(const float*)d_in[6];  ew.v1 =(const float*)d_in[7];
  ew.w2 =(const float*)d_in[8];  ew.b2 =(const float*)d_in[9];
  ew.g2 =(const float*)d_in[10]; ew.be2=(const float*)d_in[11];
  ew.m2 =(const float*)d_in[12]; ew.v2 =(const float*)d_in[13];
  ew.w3 =(const float*)d_in[14]; ew.b3 =(const float*)d_in[15];
  ew.g3 =(const float*)d_in[16]; ew.be3=(const float*)d_in[17];
  ew.m3 =(const float*)d_in[18]; ew.v3 =(const float*)d_in[19];

  prep_kernel<<<128, 256, 0, stream>>>(ew, ws);
  encode_kernel<<<dim3(256,32), 256, 0, stream>>>(src, tgt, ws, ws + WS_LAT);
  fps_kernel<<<32, 512, 0, stream>>>(src, tgt,
      (const float*)d_in[20], (const float*)d_in[21],
      (const float*)d_in[22], (const float*)d_in[23], ws, out);
  cage_mlp_kernel<<<64, 256, 0, stream>>>(ws,
      (const float*)d_in[24], (const float*)d_in[25],
      (const float*)d_in[26], (const float*)d_in[27], ws);
  deform_kernel<<<dim3(64,16), 256, 0, stream>>>(src, ws, out);
}

// Round 11
// 540.896 us; speedup vs baseline: 1.2939x; 1.2939x over previous
//
#include <hip/hip_runtime.h>

#define B_ 16
#define N_ 16384
#define K_ 16

// ---- compact workspace layout (float offsets) ----
enum : int {
  WS_LAT  = 0,      // 32 x 128 latent (f32, atomicMax-as-uint, relu>=0)
  WS_SEL  = 5632,   // 32 x 48 selected keypoints
  WS_PMIN = 7168,   // 16 x 3
  WS_PMAX = 7216,   // 16 x 3
  WS_CF   = 7264,   // 16 x 512 x 3 cage corners
  WS_W1F  = 31840,  // 64 x 3  bn-folded
  WS_B1F  = 32032,  // 64
  WS_W2T  = 32096,  // 64(c_in) x 128(out) TRANSPOSED, bn-folded
  WS_B2F  = 40288,  // 128
  WS_W3F  = 40416,  // 128(c_in) x 128(out), transposed, scale3-folded
  WS_B3F  = 56800,  // 128
  WS_END  = 56928
};

enum : int { OUT_DEF=0, OUT_SRCKP=786432, OUT_TGTKP=787200 };

__device__ __forceinline__ float dist2rn(float px,float py,float pz,float sx,float sy,float sz){
  float dx=__fsub_rn(px,sx), dy=__fsub_rn(py,sy), dz=__fsub_rn(pz,sz);
  return __fadd_rn(__fadd_rn(__fmul_rn(dx,dx),__fmul_rn(dy,dy)),__fmul_rn(dz,dz));
}

// ---------------- prep: fold BN into encoder weights, transpose w2/w3 ---------
struct EncW {
  const float *w1,*b1,*g1,*be1,*m1,*v1;
  const float *w2,*b2,*g2,*be2,*m2,*v2;
  const float *w3,*b3,*g3,*be3,*m3,*v3;
};

__device__ __forceinline__ float bn_scale(const float* g, const float* v, int ch){
  return g[ch] * (1.0f / sqrtf(v[ch] + 1e-5f));
}

__global__ void prep_kernel(EncW a, float* ws){
  const int stride = gridDim.x*blockDim.x;
  const int tid = blockIdx.x*blockDim.x + threadIdx.x;
  for (int i=tid;i<4096;i+=stride)            // zero latent (atomicMax target)
    ws[WS_LAT+i] = 0.0f;
  for (int i=tid;i<192;i+=stride){            // W1F
    int o=i/3;
    ws[WS_W1F+i] = a.w1[i] * bn_scale(a.g1,a.v1,o);
  }
  for (int i=tid;i<64;i+=stride){             // B1F = (b1-m1)*s1+be1
    float s = bn_scale(a.g1,a.v1,i);
    ws[WS_B1F+i] = (a.b1[i] - a.m1[i])*s + a.be1[i];
  }
  for (int i=tid;i<8192;i+=stride){           // W2T[c][o] = w2[o][c]*s2[o]
    int c=i>>7, o=i&127;
    ws[WS_W2T+i] = a.w2[o*64+c] * bn_scale(a.g2,a.v2,o);
  }
  for (int i=tid;i<128;i+=stride){
    float s = bn_scale(a.g2,a.v2,i);
    ws[WS_B2F+i] = (a.b2[i] - a.m2[i])*s + a.be2[i];
  }
  for (int i=tid;i<16384;i+=stride){          // W3F[c][j] = w3[j][c]*s3[j]
    int c=i>>7, j=i&127;
    ws[WS_W3F+i] = a.w3[j*128+c] * bn_scale(a.g3,a.v3,j);
  }
  for (int i=tid;i<128;i+=stride){
    float s = bn_scale(a.g3,a.v3,i);
    ws[WS_B3F+i] = (a.b3[i] - a.m3[i])*s + a.be3[i];
  }
}

// ---------------- encoder v7: P=2, 128-pt tile, h2 in EIGHTHS (40KB LDS) ------
// Variant table (measured): P=2 beats P=1 (halved per-lane ds/s_load per FMA);
// occupancy is the stall lever (R7 2blk 45% busy -> R8 3blk 54.5%). v7 = R8's
// exact P=2 structure with h2 staged through an 8KB eighth-buffer: LDS 40KB ->
// 4 blocks/CU (160/40). +2% issue (extra h1 rescans), 17 barriers/tile.
// Accumulation order (c asc, global c2 asc across eighths) bit-identical to
// v3/v4 -> identical FPS selections.
__global__ __launch_bounds__(256, 4) void encode_kernel(const float* __restrict__ src,
                                                        const float* __restrict__ tgt,
                                                        const float* __restrict__ ws,
                                                        float* __restrict__ lat){
  const int cloud = blockIdx.y;
  const int tile  = blockIdx.x;              // 128 tiles/cloud, 128 pts each
  const int t = threadIdx.x;
  const int lane = t & 63;
  const int wv = __builtin_amdgcn_readfirstlane(t >> 6);   // 0..3

  const float* base = ((cloud < B_) ? (src + (size_t)cloud*N_*3)
                                    : (tgt + (size_t)(cloud-B_)*N_*3))
                      + (size_t)tile*128*3;

  __shared__ float h1s[64*128];   // [c][pt]  32KB (full, written once)
  __shared__ float h2b[16*128];   // [eighth-ch][pt] 8KB (reused across eighths)

  const int p0 = 2*lane;
  const float x0a=base[p0*3+0], x1a=base[p0*3+1], x2a=base[p0*3+2];
  const float x0b=base[p0*3+3], x1b=base[p0*3+4], x2b=base[p0*3+5];

  // phase A: layer 1 (3->64); wave wv computes channels 16wv..16wv+15
  {
    const float* w1 = ws + WS_W1F;
    #pragma unroll
    for (int k=0;k<16;k++){
      const int o = wv*16 + k;
      const float wx=w1[o*3], wy=w1[o*3+1], wz=w1[o*3+2], bb=ws[WS_B1F+o];
      h1s[o*128+p0]   = fmaxf(fmaf(wz,x2a,fmaf(wy,x1a,wx*x0a))+bb, 0.0f);
      h1s[o*128+p0+1] = fmaxf(fmaf(wz,x2b,fmaf(wy,x1b,wx*x0b))+bb, 0.0f);
    }
  }
  __syncthreads();

  float accL[2][32];
  #pragma unroll
  for (int jj=0;jj<32;jj++){ accL[0][jj]=0.0f; accL[1][jj]=0.0f; }

  #pragma unroll 1
  for (int q=0;q<8;q++){
    // phase B: h2 channels [q*16 + wv*4, +4) for this lane's 2 points
    float acc2[2][4];
    #pragma unroll
    for (int oo=0;oo<4;oo++){ acc2[0][oo]=0.0f; acc2[1][oo]=0.0f; }
    const float* w2t = ws + WS_W2T + q*16 + wv*4;   // + c*128 + oo
    #pragma unroll 4
    for (int c=0;c<64;c++){
      const float2 a = *(const float2*)&h1s[c*128 + p0];
      #pragma unroll
      for (int oo=0;oo<4;oo++){
        const float w = w2t[c*128 + oo];
        acc2[0][oo] = fmaf(a.x, w, acc2[0][oo]);
        acc2[1][oo] = fmaf(a.y, w, acc2[1][oo]);
      }
    }
    __syncthreads();   // all waves done READING h2b (previous eighth)
    #pragma unroll
    for (int oo=0;oo<4;oo++){
      const float b = ws[WS_B2F + q*16 + wv*4 + oo];
      float2 y;
      y.x = fmaxf(acc2[0][oo]+b, 0.0f);
      y.y = fmaxf(acc2[1][oo]+b, 0.0f);
      *(float2*)&h2b[(wv*4+oo)*128 + p0] = y;
    }
    __syncthreads();

    // phase C: layer-3 partial over this eighth's 16 input channels
    #pragma unroll 2
    for (int c2=0;c2<16;c2++){
      const float2 a = *(const float2*)&h2b[c2*128 + p0];
      const float* wr = ws + WS_W3F + (q*16+c2)*128 + wv*32;
      #pragma unroll
      for (int jj=0;jj<32;jj++){
        const float w = wr[jj];
        accL[0][jj] = fmaf(a.x, w, accL[0][jj]);
        accL[1][jj] = fmaf(a.y, w, accL[1][jj]);
      }
    }
  }

  // bias+relu, max over 2 pts, wave-reduce 64 lanes, one atomic per channel
  #pragma unroll
  for (int jj=0;jj<32;jj++){
    const float b = ws[WS_B3F + wv*32 + jj];
    float x = fmaxf(fmaxf(accL[0][jj]+b, 0.0f), fmaxf(accL[1][jj]+b, 0.0f));
    #pragma unroll
    for (int off=32; off>0; off>>=1) x = fmaxf(x, __shfl_down(x, off, 64));
    if (lane==0)
      atomicMax((unsigned*)(lat + cloud*128 + wv*32 + jj), __float_as_uint(x));
  }
}

// ---------------- FPS + fused kp-MLP + fused src min/max ----------------------
// One block (512 thr) per cloud; points register-cached once (no global
// re-read across the 16 rounds). Argmax: LDS dump + single-wave butterfly.
// Tie-break: larger v, then smaller index == numpy argmax first-occurrence.
__global__ __launch_bounds__(512) void fps_kernel(const float* __restrict__ src,
                                                  const float* __restrict__ tgt,
                                                  const float* __restrict__ kw1,
                                                  const float* __restrict__ kb1,
                                                  const float* __restrict__ kw2,
                                                  const float* __restrict__ kb2,
                                                  float* ws, float* out){
  const int cloud = blockIdx.x; const int t = threadIdx.x;
  const float* base = (cloud < B_) ? (src + (size_t)cloud*N_*3)
                                   : (tgt + (size_t)(cloud-B_)*N_*3);
  __shared__ float kpl[48];
  __shared__ float h[128];
  __shared__ float rv[512]; __shared__ int ri[512];
  __shared__ float sel[3];

  // register-cache this thread's 32 points (issue loads early)
  float px[32], py[32], pz[32];
  #pragma unroll
  for (int k=0;k<32;k++){
    int n = t + k*512;
    px[k]=base[n*3]; py[k]=base[n*3+1]; pz[k]=base[n*3+2];
  }

  // fused kp MLP: lat(128) -> 128 relu -> 48  (same fmaf chains as before)
  const float* lat = ws + WS_LAT + cloud*128;
  if (t < 128){
    float acc = kb1[t];
    const float* w = kw1 + t*128;
    for (int c=0;c<128;c++) acc = fmaf(lat[c], w[c], acc);
    h[t] = fmaxf(acc, 0.0f);
  }
  __syncthreads();
  if (t < 48){
    float acc = kb2[t];
    const float* w = kw2 + t*128;
    for (int c=0;c<128;c++) acc = fmaf(h[c], w[c], acc);
    kpl[t] = acc;
  }
  __syncthreads();

  // phase A: d0 = min over proposed kps, argmax; src clouds also min/max
  float mnx=3.4e38f,mny=3.4e38f,mnz=3.4e38f, mxx=-3.4e38f,mxy=-3.4e38f,mxz=-3.4e38f;
  float bv = -1.0f; int bi = 0;
  #pragma unroll 2
  for (int k=0;k<32;k++){
    int n = t + k*512;
    if (cloud < B_){
      mnx=fminf(mnx,px[k]); mny=fminf(mny,py[k]); mnz=fminf(mnz,pz[k]);
      mxx=fmaxf(mxx,px[k]); mxy=fmaxf(mxy,py[k]); mxz=fmaxf(mxz,pz[k]);
    }
    float dmin = 3.4028235e38f;
    #pragma unroll
    for (int j=0;j<K_;j++)
      dmin = fminf(dmin, dist2rn(px[k],py[k],pz[k], kpl[j*3],kpl[j*3+1],kpl[j*3+2]));
    if (dmin > bv){ bv = dmin; bi = n; }
  }

  // block argmax -> sel, also store keypoint 0
  rv[t]=bv; ri[t]=bi;
  __syncthreads();
  if (t < 64){
    float v = rv[t]; int i = ri[t];
    #pragma unroll
    for (int e=1;e<8;e++){
      float v2=rv[t+64*e]; int i2=ri[t+64*e];
      if (v2 > v || (v2 == v && i2 < i)){ v=v2; i=i2; }
    }
    #pragma unroll
    for (int m=1;m<64;m<<=1){
      float v2=__shfl_xor(v,m,64); int i2=__shfl_xor(i,m,64);
      if (v2 > v || (v2 == v && i2 < i)){ v=v2; i=i2; }
    }
    if (t==0){
      sel[0]=base[i*3]; sel[1]=base[i*3+1]; sel[2]=base[i*3+2];
      float* sw = ws + WS_SEL + cloud*48;
      sw[0]=sel[0]; sw[1]=sel[1]; sw[2]=sel[2];
      size_t o = (cloud<B_) ? (size_t)(OUT_SRCKP + cloud*48) : (size_t)(OUT_TGTKP + (cloud-B_)*48);
      out[o]=sel[0]; out[o+1]=sel[1]; out[o+2]=sel[2];
    }
  }
  __syncthreads();

  // src-cloud min/max block reductions (exact regardless of order)
  if (cloud < B_){
    float vals[6] = {mnx,mny,mnz,mxx,mxy,mxz};
    for (int c=0;c<6;c++){
      rv[t]=vals[c];
      __syncthreads();
      if (t < 64){
        float v = rv[t];
        #pragma unroll
        for (int e=1;e<8;e++){
          float v2 = rv[t+64*e];
          v = (c<3) ? fminf(v,v2) : fmaxf(v,v2);
        }
        #pragma unroll
        for (int m=1;m<64;m<<=1){
          float v2=__shfl_xor(v,m,64);
          v = (c<3) ? fminf(v,v2) : fmaxf(v,v2);
        }
        if (t==0){
          if (c<3) ws[WS_PMIN + cloud*3 + c] = v;
          else     ws[WS_PMAX + cloud*3 + (c-3)] = v;
        }
      }
      __syncthreads();
    }
  }

  float s0=sel[0], s1=sel[1], s2=sel[2];

  // phase B: mind = dist to sel0 (fresh, per reference), track argmax
  float mind[32];
  bv = -1.0f; bi = 0;
  #pragma unroll
  for (int k=0;k<32;k++){
    int n = t + k*512;
    float d = dist2rn(px[k],py[k],pz[k], s0,s1,s2);
    mind[k]=d;
    if (d > bv){ bv=d; bi=n; }
  }

  for (int it=1; it<K_; it++){
    rv[t]=bv; ri[t]=bi;
    __syncthreads();
    if (t < 64){
      float v = rv[t]; int i = ri[t];
      #pragma unroll
      for (int e=1;e<8;e++){
        float v2=rv[t+64*e]; int i2=ri[t+64*e];
        if (v2 > v || (v2 == v && i2 < i)){ v=v2; i=i2; }
      }
      #pragma unroll
      for (int m=1;m<64;m<<=1){
        float v2=__shfl_xor(v,m,64); int i2=__shfl_xor(i,m,64);
        if (v2 > v || (v2 == v && i2 < i)){ v=v2; i=i2; }
      }
      if (t==0){
        sel[0]=base[i*3]; sel[1]=base[i*3+1]; sel[2]=base[i*3+2];
        float* sw = ws + WS_SEL + cloud*48 + it*3;
        sw[0]=sel[0]; sw[1]=sel[1]; sw[2]=sel[2];
        size_t o = (cloud<B_) ? (size_t)(OUT_SRCKP + cloud*48 + it*3)
                              : (size_t)(OUT_TGTKP + (cloud-B_)*48 + it*3);
        out[o]=sel[0]; out[o+1]=sel[1]; out[o+2]=sel[2];
      }
    }
    __syncthreads();
    s0=sel[0]; s1=sel[1]; s2=sel[2];
    if (it < K_-1){
      bv=-1.0f; bi=0;
      #pragma unroll
      for (int k=0;k<32;k++){
        int n = t + k*512;
        float d = dist2rn(px[k],py[k],pz[k], s0,s1,s2);
        float m = fminf(mind[k], d);
        mind[k]=m;
        if (m > bv){ bv=m; bi=n; }
      }
    }
  }
}

// ---------------- cage MLP + corner grid (64 blocks) --------------------------
__global__ void cage_mlp_kernel(const float* __restrict__ ws,
                                const float* __restrict__ cw1, const float* __restrict__ cb1,
                                const float* __restrict__ cw2, const float* __restrict__ cb2,
                                float* __restrict__ wsm){
  const int b = blockIdx.x >> 2, part = blockIdx.x & 3;
  const int t = threadIdx.x;
  __shared__ float diff[48]; __shared__ float h[128];
  if (t<48) diff[t] = __fsub_rn(ws[WS_SEL + (B_+b)*48 + t], ws[WS_SEL + b*48 + t]);
  __syncthreads();
  if (t<128){
    const float* w = cw1 + t*48;
    float acc = cb1[t];
    for (int j=0;j<48;j++) acc = fmaf(diff[j], w[j], acc);
    h[t] = fmaxf(acc, 0.0f);
  }
  __syncthreads();
  for (int o = part*384 + t; o < part*384 + 384; o += 256){
    const float* w = cw2 + o*128;
    float acc = cb2[o];
    for (int c=0;c<128;c++) acc = fmaf(h[c], w[c], acc);
    int flat = o/3, coord = o - flat*3;
    int u = flat>>6, v=(flat>>3)&7, z=flat&7;
    int g = (coord==0)?u:((coord==1)?v:z);
    float gv = (g==7)?1.0f:(float)g*(1.0f/7.0f);
    wsm[WS_CF + b*1536 + o] = gv + acc;
  }
}

// ---------------- trilinear cage deform ---------------------------------------
__global__ __launch_bounds__(256) void deform_kernel(const float* __restrict__ src,
                                                     const float* __restrict__ ws,
                                                     float* __restrict__ out){
  const int b = blockIdx.y;
  const int n = blockIdx.x*256 + threadIdx.x;
  __shared__ float cf[1536];
  for (int i=threadIdx.x;i<1536;i+=256) cf[i] = ws[WS_CF + b*1536 + i];
  __syncthreads();

  const float* p = src + ((size_t)b*N_ + n)*3;
  float pt[3]; int id[3]; float w[3];
  #pragma unroll
  for (int c=0;c<3;c++){
    float pv = p[c];
    float mn = ws[WS_PMIN+b*3+c], mxv = ws[WS_PMAX+b*3+c];
    float denom = __fadd_rn(__fsub_rn(mxv, mn), 1e-6f);
    float tc = __fmul_rn(__fdiv_rn(__fsub_rn(pv, mn), denom), 7.0f);
    int ic = (int)tc; ic = min(max(ic,0),6);
    pt[c]=pv; id[c]=ic; w[c]=__fsub_rn(tc, (float)ic);
  }
  const int flat = (id[0]<<6) + (id[1]<<3) + id[2];
  const float* c000 = cf + flat*3;
  const float wx=w[0], wy=w[1], wz=w[2];
  const float ux=__fsub_rn(1.0f,wx), uy=__fsub_rn(1.0f,wy), uz=__fsub_rn(1.0f,wz);
  const float w000=__fmul_rn(__fmul_rn(ux,uy),uz);
  const float w100=__fmul_rn(__fmul_rn(wx,uy),uz);
  const float w010=__fmul_rn(__fmul_rn(ux,wy),uz);
  const float w110=__fmul_rn(__fmul_rn(wx,wy),uz);
  const float w001=__fmul_rn(__fmul_rn(ux,uy),wz);
  const float w101=__fmul_rn(__fmul_rn(wx,uy),wz);
  const float w011=__fmul_rn(__fmul_rn(ux,wy),wz);
  const float w111=__fmul_rn(__fmul_rn(wx,wy),wz);
  #pragma unroll
  for (int c=0;c<3;c++){
    float d = __fmul_rn(w000, c000[c]);
    d = __fadd_rn(d, __fmul_rn(w100, c000[192+c]));  // (+1,0,0) -> +64*3
    d = __fadd_rn(d, __fmul_rn(w010, c000[24+c]));   // (0,+1,0) -> +8*3
    d = __fadd_rn(d, __fmul_rn(w110, c000[216+c]));
    d = __fadd_rn(d, __fmul_rn(w001, c000[3+c]));    // (0,0,+1) -> +3
    d = __fadd_rn(d, __fmul_rn(w101, c000[195+c]));
    d = __fadd_rn(d, __fmul_rn(w011, c000[27+c]));
    d = __fadd_rn(d, __fmul_rn(w111, c000[219+c]));
    out[((size_t)b*N_+n)*3 + c] = __fadd_rn(pt[c], d);
  }
}

// ---------------- launch ------------------------------------------------------
extern "C" void kernel_launch(void* const* d_in, const int* in_sizes, int n_in,
                              void* d_out, int out_size, void* d_ws, size_t ws_size,
                              hipStream_t stream){
  const float* src = (const float*)d_in[0];
  const float* tgt = (const float*)d_in[1];
  float* ws = (float*)d_ws;
  float* out = (float*)d_out;

  EncW ew;
  ew.w1 =(const float*)d_in[2];  ew.b1 =(const float*)d_in[3];
  ew.g1 =(const float*)d_in[4];  ew.be1=(const float*)d_in[5];
  ew.m1 =(const float*)d_in[6];  ew.v1 =(const float*)d_in[7];
  ew.w2 =(const float*)d_in[8];  ew.b2 =(const float*)d_in[9];
  ew.g2 =(const float*)d_in[10]; ew.be2=(const float*)d_in[11];
  ew.m2 =(const float*)d_in[12]; ew.v2 =(const float*)d_in[13];
  ew.w3 =(const float*)d_in[14]; ew.b3 =(const float*)d_in[15];
  ew.g3 =(const float*)d_in[16]; ew.be3=(const float*)d_in[17];
  ew.m3 =(const float*)d_in[18]; ew.v3 =(const float*)d_in[19];

  prep_kernel<<<128, 256, 0, stream>>>(ew, ws);
  encode_kernel<<<dim3(128,32), 256, 0, stream>>>(src, tgt, ws, ws + WS_LAT);
  fps_kernel<<<32, 512, 0, stream>>>(src, tgt,
      (const float*)d_in[20], (const float*)d_in[21],
      (const float*)d_in[22], (const float*)d_in[23], ws, out);
  cage_mlp_kernel<<<64, 256, 0, stream>>>(ws,
      (const float*)d_in[24], (const float*)d_in[25],
      (const float*)d_in[26], (const float*)d_in[27], ws);
  deform_kernel<<<dim3(64,16), 256, 0, stream>>>(src, ws, out);
}

// Round 12
// 517.301 us; speedup vs baseline: 1.3529x; 1.0456x over previous
//
#include <hip/hip_runtime.h>

#define B_ 16
#define N_ 16384
#define K_ 16

// ---- compact workspace layout (float offsets) ----
enum : int {
  WS_LAT  = 0,      // 32 x 128 latent (f32, atomicMax-as-uint, relu>=0)
  WS_SEL  = 5632,   // 32 x 48 selected keypoints
  WS_PMIN = 7168,   // 16 x 3
  WS_PMAX = 7216,   // 16 x 3
  WS_CF   = 7264,   // 16 x 512 x 3 cage corners
  WS_W1F  = 31840,  // 64 x 3  bn-folded
  WS_B1F  = 32032,  // 64
  WS_W2T  = 32096,  // 64(c_in) x 128(out) TRANSPOSED, bn-folded
  WS_B2F  = 40288,  // 128
  WS_W3F  = 40416,  // 128(c_in) x 128(out), transposed, scale3-folded
  WS_B3F  = 56800,  // 128
  WS_END  = 56928
};

enum : int { OUT_DEF=0, OUT_SRCKP=786432, OUT_TGTKP=787200 };

__device__ __forceinline__ float dist2rn(float px,float py,float pz,float sx,float sy,float sz){
  float dx=__fsub_rn(px,sx), dy=__fsub_rn(py,sy), dz=__fsub_rn(pz,sz);
  return __fadd_rn(__fadd_rn(__fmul_rn(dx,dx),__fmul_rn(dy,dy)),__fmul_rn(dz,dz));
}

// ---------------- prep: fold BN into encoder weights, transpose w2/w3 ---------
struct EncW {
  const float *w1,*b1,*g1,*be1,*m1,*v1;
  const float *w2,*b2,*g2,*be2,*m2,*v2;
  const float *w3,*b3,*g3,*be3,*m3,*v3;
};

__device__ __forceinline__ float bn_scale(const float* g, const float* v, int ch){
  return g[ch] * (1.0f / sqrtf(v[ch] + 1e-5f));
}

__global__ void prep_kernel(EncW a, float* ws){
  const int stride = gridDim.x*blockDim.x;
  const int tid = blockIdx.x*blockDim.x + threadIdx.x;
  for (int i=tid;i<4096;i+=stride)            // zero latent (atomicMax target)
    ws[WS_LAT+i] = 0.0f;
  for (int i=tid;i<192;i+=stride){            // W1F
    int o=i/3;
    ws[WS_W1F+i] = a.w1[i] * bn_scale(a.g1,a.v1,o);
  }
  for (int i=tid;i<64;i+=stride){             // B1F = (b1-m1)*s1+be1
    float s = bn_scale(a.g1,a.v1,i);
    ws[WS_B1F+i] = (a.b1[i] - a.m1[i])*s + a.be1[i];
  }
  for (int i=tid;i<8192;i+=stride){           // W2T[c][o] = w2[o][c]*s2[o]
    int c=i>>7, o=i&127;
    ws[WS_W2T+i] = a.w2[o*64+c] * bn_scale(a.g2,a.v2,o);
  }
  for (int i=tid;i<128;i+=stride){
    float s = bn_scale(a.g2,a.v2,i);
    ws[WS_B2F+i] = (a.b2[i] - a.m2[i])*s + a.be2[i];
  }
  for (int i=tid;i<16384;i+=stride){          // W3F[c][j] = w3[j][c]*s3[j]
    int c=i>>7, j=i&127;
    ws[WS_W3F+i] = a.w3[j*128+c] * bn_scale(a.g3,a.v3,j);
  }
  for (int i=tid;i<128;i+=stride){
    float s = bn_scale(a.g3,a.v3,i);
    ws[WS_B3F+i] = (a.b3[i] - a.m3[i])*s + a.be3[i];
  }
}

// ---------------- encoder v8: 512-thr (8-wave) blocks, 8 waves/SIMD -----------
// R11 validated the occupancy->busy ladder (2/3/4 blk -> 45/54.5/61.3% busy);
// issue time is pinned at ~225us (1.36x FMA floor). v8 halves per-wave channel
// ownership (8 waves: 16 latent ch/wave -> accL[2][16]=32 regs, live ~55) so
// __launch_bounds__(512,8) fits the 64-reg budget -> 4x512-thr blocks/CU =
// 8 waves/SIMD at the same 40KB LDS. FMA/ds counts and accumulation order
// (c asc, global c2 asc) identical to v7 -> same FPS selections.
__global__ __launch_bounds__(512, 8) void encode_kernel(const float* __restrict__ src,
                                                        const float* __restrict__ tgt,
                                                        const float* __restrict__ ws,
                                                        float* __restrict__ lat){
  const int cloud = blockIdx.y;
  const int tile  = blockIdx.x;              // 128 tiles/cloud, 128 pts each
  const int t = threadIdx.x;
  const int lane = t & 63;
  const int wv = __builtin_amdgcn_readfirstlane(t >> 6);   // 0..7

  const float* base = ((cloud < B_) ? (src + (size_t)cloud*N_*3)
                                    : (tgt + (size_t)(cloud-B_)*N_*3))
                      + (size_t)tile*128*3;

  __shared__ float h1s[64*128];   // [c][pt]  32KB (full, written once)
  __shared__ float h2b[16*128];   // [eighth-ch][pt] 8KB (reused across eighths)

  const int p0 = 2*lane;

  // phase A: layer 1 (3->64); wave wv computes channels 8wv..8wv+7
  {
    const float x0a=base[p0*3+0], x1a=base[p0*3+1], x2a=base[p0*3+2];
    const float x0b=base[p0*3+3], x1b=base[p0*3+4], x2b=base[p0*3+5];
    const float* w1 = ws + WS_W1F;
    #pragma unroll
    for (int k=0;k<8;k++){
      const int o = wv*8 + k;
      const float wx=w1[o*3], wy=w1[o*3+1], wz=w1[o*3+2], bb=ws[WS_B1F+o];
      h1s[o*128+p0]   = fmaxf(fmaf(wz,x2a,fmaf(wy,x1a,wx*x0a))+bb, 0.0f);
      h1s[o*128+p0+1] = fmaxf(fmaf(wz,x2b,fmaf(wy,x1b,wx*x0b))+bb, 0.0f);
    }
  }
  __syncthreads();

  float accL[2][16];
  #pragma unroll
  for (int jj=0;jj<16;jj++){ accL[0][jj]=0.0f; accL[1][jj]=0.0f; }

  #pragma unroll 1
  for (int q=0;q<8;q++){
    // phase B: h2 channels [q*16 + wv*2, +2) for this lane's 2 points
    float acc2[2][2];
    acc2[0][0]=0.0f; acc2[0][1]=0.0f; acc2[1][0]=0.0f; acc2[1][1]=0.0f;
    const float* w2t = ws + WS_W2T + q*16 + wv*2;   // + c*128 + oo
    #pragma unroll 4
    for (int c=0;c<64;c++){
      const float2 a = *(const float2*)&h1s[c*128 + p0];
      #pragma unroll
      for (int oo=0;oo<2;oo++){
        const float w = w2t[c*128 + oo];
        acc2[0][oo] = fmaf(a.x, w, acc2[0][oo]);
        acc2[1][oo] = fmaf(a.y, w, acc2[1][oo]);
      }
    }
    __syncthreads();   // all waves done READING h2b (previous eighth)
    #pragma unroll
    for (int oo=0;oo<2;oo++){
      const float b = ws[WS_B2F + q*16 + wv*2 + oo];
      float2 y;
      y.x = fmaxf(acc2[0][oo]+b, 0.0f);
      y.y = fmaxf(acc2[1][oo]+b, 0.0f);
      *(float2*)&h2b[(wv*2+oo)*128 + p0] = y;
    }
    __syncthreads();

    // phase C: layer-3 partial over this eighth's 16 input channels
    #pragma unroll 2
    for (int c2=0;c2<16;c2++){
      const float2 a = *(const float2*)&h2b[c2*128 + p0];
      const float* wr = ws + WS_W3F + (q*16+c2)*128 + wv*16;
      #pragma unroll
      for (int jj=0;jj<16;jj++){
        const float w = wr[jj];
        accL[0][jj] = fmaf(a.x, w, accL[0][jj]);
        accL[1][jj] = fmaf(a.y, w, accL[1][jj]);
      }
    }
  }

  // bias+relu, max over 2 pts, wave-reduce 64 lanes, one atomic per channel
  #pragma unroll
  for (int jj=0;jj<16;jj++){
    const float b = ws[WS_B3F + wv*16 + jj];
    float x = fmaxf(fmaxf(accL[0][jj]+b, 0.0f), fmaxf(accL[1][jj]+b, 0.0f));
    #pragma unroll
    for (int off=32; off>0; off>>=1) x = fmaxf(x, __shfl_down(x, off, 64));
    if (lane==0)
      atomicMax((unsigned*)(lat + cloud*128 + wv*16 + jj), __float_as_uint(x));
  }
}

// ---------------- FPS + fused kp-MLP + fused src min/max ----------------------
// One block (512 thr) per cloud; points register-cached once (no global
// re-read across the 16 rounds). Argmax: LDS dump + single-wave butterfly.
// Tie-break: larger v, then smaller index == numpy argmax first-occurrence.
__global__ __launch_bounds__(512) void fps_kernel(const float* __restrict__ src,
                                                  const float* __restrict__ tgt,
                                                  const float* __restrict__ kw1,
                                                  const float* __restrict__ kb1,
                                                  const float* __restrict__ kw2,
                                                  const float* __restrict__ kb2,
                                                  float* ws, float* out){
  const int cloud = blockIdx.x; const int t = threadIdx.x;
  const float* base = (cloud < B_) ? (src + (size_t)cloud*N_*3)
                                   : (tgt + (size_t)(cloud-B_)*N_*3);
  __shared__ float kpl[48];
  __shared__ float h[128];
  __shared__ float rv[512]; __shared__ int ri[512];
  __shared__ float sel[3];

  // register-cache this thread's 32 points (issue loads early)
  float px[32], py[32], pz[32];
  #pragma unroll
  for (int k=0;k<32;k++){
    int n = t + k*512;
    px[k]=base[n*3]; py[k]=base[n*3+1]; pz[k]=base[n*3+2];
  }

  // fused kp MLP: lat(128) -> 128 relu -> 48  (same fmaf chains as before)
  const float* lat = ws + WS_LAT + cloud*128;
  if (t < 128){
    float acc = kb1[t];
    const float* w = kw1 + t*128;
    for (int c=0;c<128;c++) acc = fmaf(lat[c], w[c], acc);
    h[t] = fmaxf(acc, 0.0f);
  }
  __syncthreads();
  if (t < 48){
    float acc = kb2[t];
    const float* w = kw2 + t*128;
    for (int c=0;c<128;c++) acc = fmaf(h[c], w[c], acc);
    kpl[t] = acc;
  }
  __syncthreads();

  // phase A: d0 = min over proposed kps, argmax; src clouds also min/max
  float mnx=3.4e38f,mny=3.4e38f,mnz=3.4e38f, mxx=-3.4e38f,mxy=-3.4e38f,mxz=-3.4e38f;
  float bv = -1.0f; int bi = 0;
  #pragma unroll 2
  for (int k=0;k<32;k++){
    int n = t + k*512;
    if (cloud < B_){
      mnx=fminf(mnx,px[k]); mny=fminf(mny,py[k]); mnz=fminf(mnz,pz[k]);
      mxx=fmaxf(mxx,px[k]); mxy=fmaxf(mxy,py[k]); mxz=fmaxf(mxz,pz[k]);
    }
    float dmin = 3.4028235e38f;
    #pragma unroll
    for (int j=0;j<K_;j++)
      dmin = fminf(dmin, dist2rn(px[k],py[k],pz[k], kpl[j*3],kpl[j*3+1],kpl[j*3+2]));
    if (dmin > bv){ bv = dmin; bi = n; }
  }

  // block argmax -> sel, also store keypoint 0
  rv[t]=bv; ri[t]=bi;
  __syncthreads();
  if (t < 64){
    float v = rv[t]; int i = ri[t];
    #pragma unroll
    for (int e=1;e<8;e++){
      float v2=rv[t+64*e]; int i2=ri[t+64*e];
      if (v2 > v || (v2 == v && i2 < i)){ v=v2; i=i2; }
    }
    #pragma unroll
    for (int m=1;m<64;m<<=1){
      float v2=__shfl_xor(v,m,64); int i2=__shfl_xor(i,m,64);
      if (v2 > v || (v2 == v && i2 < i)){ v=v2; i=i2; }
    }
    if (t==0){
      sel[0]=base[i*3]; sel[1]=base[i*3+1]; sel[2]=base[i*3+2];
      float* sw = ws + WS_SEL + cloud*48;
      sw[0]=sel[0]; sw[1]=sel[1]; sw[2]=sel[2];
      size_t o = (cloud<B_) ? (size_t)(OUT_SRCKP + cloud*48) : (size_t)(OUT_TGTKP + (cloud-B_)*48);
      out[o]=sel[0]; out[o+1]=sel[1]; out[o+2]=sel[2];
    }
  }
  __syncthreads();

  // src-cloud min/max block reductions (exact regardless of order)
  if (cloud < B_){
    float vals[6] = {mnx,mny,mnz,mxx,mxy,mxz};
    for (int c=0;c<6;c++){
      rv[t]=vals[c];
      __syncthreads();
      if (t < 64){
        float v = rv[t];
        #pragma unroll
        for (int e=1;e<8;e++){
          float v2 = rv[t+64*e];
          v = (c<3) ? fminf(v,v2) : fmaxf(v,v2);
        }
        #pragma unroll
        for (int m=1;m<64;m<<=1){
          float v2=__shfl_xor(v,m,64);
          v = (c<3) ? fminf(v,v2) : fmaxf(v,v2);
        }
        if (t==0){
          if (c<3) ws[WS_PMIN + cloud*3 + c] = v;
          else     ws[WS_PMAX + cloud*3 + (c-3)] = v;
        }
      }
      __syncthreads();
    }
  }

  float s0=sel[0], s1=sel[1], s2=sel[2];

  // phase B: mind = dist to sel0 (fresh, per reference), track argmax
  float mind[32];
  bv = -1.0f; bi = 0;
  #pragma unroll
  for (int k=0;k<32;k++){
    int n = t + k*512;
    float d = dist2rn(px[k],py[k],pz[k], s0,s1,s2);
    mind[k]=d;
    if (d > bv){ bv=d; bi=n; }
  }

  for (int it=1; it<K_; it++){
    rv[t]=bv; ri[t]=bi;
    __syncthreads();
    if (t < 64){
      float v = rv[t]; int i = ri[t];
      #pragma unroll
      for (int e=1;e<8;e++){
        float v2=rv[t+64*e]; int i2=ri[t+64*e];
        if (v2 > v || (v2 == v && i2 < i)){ v=v2; i=i2; }
      }
      #pragma unroll
      for (int m=1;m<64;m<<=1){
        float v2=__shfl_xor(v,m,64); int i2=__shfl_xor(i,m,64);
        if (v2 > v || (v2 == v && i2 < i)){ v=v2; i=i2; }
      }
      if (t==0){
        sel[0]=base[i*3]; sel[1]=base[i*3+1]; sel[2]=base[i*3+2];
        float* sw = ws + WS_SEL + cloud*48 + it*3;
        sw[0]=sel[0]; sw[1]=sel[1]; sw[2]=sel[2];
        size_t o = (cloud<B_) ? (size_t)(OUT_SRCKP + cloud*48 + it*3)
                              : (size_t)(OUT_TGTKP + (cloud-B_)*48 + it*3);
        out[o]=sel[0]; out[o+1]=sel[1]; out[o+2]=sel[2];
      }
    }
    __syncthreads();
    s0=sel[0]; s1=sel[1]; s2=sel[2];
    if (it < K_-1){
      bv=-1.0f; bi=0;
      #pragma unroll
      for (int k=0;k<32;k++){
        int n = t + k*512;
        float d = dist2rn(px[k],py[k],pz[k], s0,s1,s2);
        float m = fminf(mind[k], d);
        mind[k]=m;
        if (m > bv){ bv=m; bi=n; }
      }
    }
  }
}

// ---------------- cage MLP + corner grid (64 blocks) --------------------------
__global__ void cage_mlp_kernel(const float* __restrict__ ws,
                                const float* __restrict__ cw1, const float* __restrict__ cb1,
                                const float* __restrict__ cw2, const float* __restrict__ cb2,
                                float* __restrict__ wsm){
  const int b = blockIdx.x >> 2, part = blockIdx.x & 3;
  const int t = threadIdx.x;
  __shared__ float diff[48]; __shared__ float h[128];
  if (t<48) diff[t] = __fsub_rn(ws[WS_SEL + (B_+b)*48 + t], ws[WS_SEL + b*48 + t]);
  __syncthreads();
  if (t<128){
    const float* w = cw1 + t*48;
    float acc = cb1[t];
    for (int j=0;j<48;j++) acc = fmaf(diff[j], w[j], acc);
    h[t] = fmaxf(acc, 0.0f);
  }
  __syncthreads();
  for (int o = part*384 + t; o < part*384 + 384; o += 256){
    const float* w = cw2 + o*128;
    float acc = cb2[o];
    for (int c=0;c<128;c++) acc = fmaf(h[c], w[c], acc);
    int flat = o/3, coord = o - flat*3;
    int u = flat>>6, v=(flat>>3)&7, z=flat&7;
    int g = (coord==0)?u:((coord==1)?v:z);
    float gv = (g==7)?1.0f:(float)g*(1.0f/7.0f);
    wsm[WS_CF + b*1536 + o] = gv + acc;
  }
}

// ---------------- trilinear cage deform ---------------------------------------
__global__ __launch_bounds__(256) void deform_kernel(const float* __restrict__ src,
                                                     const float* __restrict__ ws,
                                                     float* __restrict__ out){
  const int b = blockIdx.y;
  const int n = blockIdx.x*256 + threadIdx.x;
  __shared__ float cf[1536];
  for (int i=threadIdx.x;i<1536;i+=256) cf[i] = ws[WS_CF + b*1536 + i];
  __syncthreads();

  const float* p = src + ((size_t)b*N_ + n)*3;
  float pt[3]; int id[3]; float w[3];
  #pragma unroll
  for (int c=0;c<3;c++){
    float pv = p[c];
    float mn = ws[WS_PMIN+b*3+c], mxv = ws[WS_PMAX+b*3+c];
    float denom = __fadd_rn(__fsub_rn(mxv, mn), 1e-6f);
    float tc = __fmul_rn(__fdiv_rn(__fsub_rn(pv, mn), denom), 7.0f);
    int ic = (int)tc; ic = min(max(ic,0),6);
    pt[c]=pv; id[c]=ic; w[c]=__fsub_rn(tc, (float)ic);
  }
  const int flat = (id[0]<<6) + (id[1]<<3) + id[2];
  const float* c000 = cf + flat*3;
  const float wx=w[0], wy=w[1], wz=w[2];
  const float ux=__fsub_rn(1.0f,wx), uy=__fsub_rn(1.0f,wy), uz=__fsub_rn(1.0f,wz);
  const float w000=__fmul_rn(__fmul_rn(ux,uy),uz);
  const float w100=__fmul_rn(__fmul_rn(wx,uy),uz);
  const float w010=__fmul_rn(__fmul_rn(ux,wy),uz);
  const float w110=__fmul_rn(__fmul_rn(wx,wy),uz);
  const float w001=__fmul_rn(__fmul_rn(ux,uy),wz);
  const float w101=__fmul_rn(__fmul_rn(wx,uy),wz);
  const float w011=__fmul_rn(__fmul_rn(ux,wy),wz);
  const float w111=__fmul_rn(__fmul_rn(wx,wy),wz);
  #pragma unroll
  for (int c=0;c<3;c++){
    float d = __fmul_rn(w000, c000[c]);
    d = __fadd_rn(d, __fmul_rn(w100, c000[192+c]));  // (+1,0,0) -> +64*3
    d = __fadd_rn(d, __fmul_rn(w010, c000[24+c]));   // (0,+1,0) -> +8*3
    d = __fadd_rn(d, __fmul_rn(w110, c000[216+c]));
    d = __fadd_rn(d, __fmul_rn(w001, c000[3+c]));    // (0,0,+1) -> +3
    d = __fadd_rn(d, __fmul_rn(w101, c000[195+c]));
    d = __fadd_rn(d, __fmul_rn(w011, c000[27+c]));
    d = __fadd_rn(d, __fmul_rn(w111, c000[219+c]));
    out[((size_t)b*N_+n)*3 + c] = __fadd_rn(pt[c], d);
  }
}

// ---------------- launch ------------------------------------------------------
extern "C" void kernel_launch(void* const* d_in, const int* in_sizes, int n_in,
                              void* d_out, int out_size, void* d_ws, size_t ws_size,
                              hipStream_t stream){
  const float* src = (const float*)d_in[0];
  const float* tgt = (const float*)d_in[1];
  float* ws = (float*)d_ws;
  float* out = (float*)d_out;

  EncW ew;
  ew.w1 =(const float*)d_in[2];  ew.b1 =(const float*)d_in[3];
  ew.g1 =(const float*)d_in[4];  ew.be1=(const float*)d_in[5];
  ew.m1 =(const float*)d_in[6];  ew.v1 =(const float*)d_in[7];
  ew.w2 =(const float*)d_in[8];  ew.b2 =(const float*)d_in[9];
  ew.g2 =(const float*)d_in[10]; ew.be2=(const float*)d_in[11];
  ew.m2 =(const float*)d_in[12]; ew.v2 =(const float*)d_in[13];
  ew.w3 =(const float*)d_in[14]; ew.b3 =(const float*)d_in[15];
  ew.g3 =(const float*)d_in[16]; ew.be3=(const float*)d_in[17];
  ew.m3 =(const float*)d_in[18]; ew.v3 =(const float*)d_in[19];

  prep_kernel<<<128, 256, 0, stream>>>(ew, ws);
  encode_kernel<<<dim3(128,32), 512, 0, stream>>>(src, tgt, ws, ws + WS_LAT);
  fps_kernel<<<32, 512, 0, stream>>>(src, tgt,
      (const float*)d_in[20], (const float*)d_in[21],
      (const float*)d_in[22], (const float*)d_in[23], ws, out);
  cage_mlp_kernel<<<64, 256, 0, stream>>>(ws,
      (const float*)d_in[24], (const float*)d_in[25],
      (const float*)d_in[26], (const float*)d_in[27], ws);
  deform_kernel<<<dim3(64,16), 256, 0, stream>>>(src, ws, out);
}